// Round 1
// baseline (292.550 us; speedup 1.0000x reference)
//
#include <hip/hip_runtime.h>

// TNNCell scan: B=4096 chains, T=512 steps, 16 lanes per chain, 4 chains per wave.
// grid = 1024 blocks x 64 threads (1 wave/block) -> 1024 waves = 1 wave/SIMD.

#define SWZ(v, m) __int_as_float(__builtin_amdgcn_ds_swizzle(__float_as_int(v), (((m) << 10) | 0x1F)))

__device__ __forceinline__ float bperm(float v, int idx_bytes) {
  return __int_as_float(__builtin_amdgcn_ds_bpermute(idx_bytes, __float_as_int(v)));
}

__global__ __launch_bounds__(64, 1) void tnn_scan(
    const float* __restrict__ in,    // (4096, 512, 7)
    const float* __restrict__ caps,  // (1, 4)
    const float* __restrict__ Wg,    // (11, 15)
    const float* __restrict__ bg,    // (15)
    const float* __restrict__ Wp1,   // (11, 16)
    const float* __restrict__ bp1,   // (16)
    const float* __restrict__ Wp2,   // (16, 4)
    const float* __restrict__ bp2,   // (4)
    float* __restrict__ out)         // (4096, 512, 4)
{
  // LDS x-stage: 2 buffers x 4 elems x 448 dwords (+1 pad so the 4 groups'
  // broadcast reads hit different banks).
  __shared__ float xb[2][4][449];

  const int lane  = threadIdx.x;      // 0..63
  const int grp   = lane >> 4;        // chain within wave: 0..3
  const int u     = lane & 15;        // unit lane within chain
  const int ur    = u & 3;            // state row this lane mirrors
  const int gbase = lane & 48;        // wave-lane base of this 16-group

  const int elem = (int)blockIdx.x * 4 + grp;

  // ---- per-lane weight columns (registers, loaded once) ----
  const int ug = (u < 15) ? u : 14;   // conduct col (col 14 is dead; lane15 dups it)
  const float wg0 = Wg[0*15+ug], wg1 = Wg[1*15+ug], wg2 = Wg[2*15+ug],
              wg3 = Wg[3*15+ug], wg4 = Wg[4*15+ug], wg5 = Wg[5*15+ug],
              wg6 = Wg[6*15+ug], wg7 = Wg[7*15+ug], wg8 = Wg[8*15+ug],
              wg9 = Wg[9*15+ug], wg10 = Wg[10*15+ug];
  const float bgc = bg[ug];
  const float wp0 = Wp1[0*16+u], wp1 = Wp1[1*16+u], wp2 = Wp1[2*16+u],
              wp3 = Wp1[3*16+u], wp4 = Wp1[4*16+u], wp5 = Wp1[5*16+u],
              wp6 = Wp1[6*16+u], wp7 = Wp1[7*16+u], wp8 = Wp1[8*16+u],
              wp9 = Wp1[9*16+u], wp10 = Wp1[10*16+u];
  const float bhc = bp1[u];
  const float w20 = Wp2[u*4+0], w21 = Wp2[u*4+1], w22 = Wp2[u*4+2], w23 = Wp2[u*4+3];
  const float bp2c = bp2[ur];
  // 0.5 * 10^caps[row]
  const float kcap = 0.5f * __expf(caps[ur] * 2.302585092994046f);

  // ---- adjacency gather indices (bytes, wave-relative) ----
  // row0:{0,1,2,3,4} row1:{0,5,6,7,8} row2:{1,5,9,10,11} row3:{2,6,9,12,13}
  const unsigned pk = (ur == 0) ? 0x43210u : (ur == 1) ? 0x87650u
                    : (ur == 2) ? 0xBA951u : 0xDC962u;
  const int gi0 = (gbase + (int)( pk        & 15u)) << 2;
  const int gi1 = (gbase + (int)((pk >>  4) & 15u)) << 2;
  const int gi2 = (gbase + (int)((pk >>  8) & 15u)) << 2;
  const int gi3 = (gbase + (int)((pk >> 12) & 15u)) << 2;
  const int gi4 = (gbase + (int)((pk >> 16) & 15u)) << 2;
  const int bi0 = (gbase + 0) << 2, bi1 = (gbase + 1) << 2,
            bi2 = (gbase + 2) << 2, bi3 = (gbase + 3) << 2;

  // per-lane temp-select masks (j-list of row ur, ascending, excluding ur)
  const bool m0 = (ur == 0), m1 = (ur <= 1), m2 = (ur <= 2);
  const bool b01 = (ur & 1), b23 = ((ur & 2) != 0);
  const bool isrow = (u < 4);

  // ---- state (s0..s3 replicated on all lanes; sown = row-ur trajectory) ----
  float s0 = 0.f, s1 = 0.f, s2 = 0.f, s3 = 0.f, sown = 0.f;

  const float* inblk = in + (size_t)((int)blockIdx.x * 4) * 3584;  // 512*7
  float* op = out + (size_t)elem * 2048 + ur;                       // 512*4

  // ---- chunked double-buffered staging (per-wave, no barriers) ----
  float stg[4][7];
  auto LOADC = [&](int cc) {
    #pragma unroll
    for (int e = 0; e < 4; ++e)
      #pragma unroll
      for (int k = 0; k < 7; ++k)
        stg[e][k] = inblk[(size_t)e * 3584 + cc * 448 + k * 64 + lane];
  };
  auto WRITEC = [&](int bb) {
    #pragma unroll
    for (int e = 0; e < 4; ++e)
      #pragma unroll
      for (int k = 0; k < 7; ++k)
        xb[bb][e][k * 64 + lane] = stg[e][k];
  };

  LOADC(0);
  WRITEC(0);

  #pragma unroll 1
  for (int c = 0; c < 8; ++c) {
    if (c < 7) LOADC(c + 1);          // prefetch next chunk (64 steps of slack)
    const int cb = c & 1;

    #pragma unroll 4
    for (int tin = 0; tin < 64; ++tin) {
      const int t = c * 64 + tin;
      const float* xr = &xb[cb][grp][tin * 7];
      const float x0 = xr[0], x1 = xr[1], x2 = xr[2], x3 = xr[3],
                  x4 = xr[4], x5 = xr[5], x6 = xr[6];

      // layer-1 dots: all_in = [x0..x4, s0..s3, x5, x6], split for latency
      float zgA = fmaf(x0, wg0, fmaf(x2, wg2, fmaf(x4, wg4,
                  fmaf(s1, wg6, fmaf(s3, wg8, fmaf(x6, wg10, bgc))))));
      float zgB = fmaf(x1, wg1, fmaf(x3, wg3, fmaf(s0, wg5,
                  fmaf(s2, wg7, x5 * wg9))));
      float zhA = fmaf(x0, wp0, fmaf(x2, wp2, fmaf(x4, wp4,
                  fmaf(s1, wp6, fmaf(s3, wp8, fmaf(x6, wp10, bhc))))));
      float zhB = fmaf(x1, wp1, fmaf(x3, wp3, fmaf(s0, wp5,
                  fmaf(s2, wp7, x5 * wp9))));
      const float zg = zgA + zgB;
      const float zh = zhA + zhB;

      const float g = __fdividef(1.0f, 1.0f + __expf(-zg));            // sigmoid
      const float h = 1.0f - 2.0f * __fdividef(1.0f, 1.0f + __expf(2.0f * zh)); // tanh

      // ploss: 16->4 dense layer, 4-stage XOR butterfly over the 16-group
      float p0 = h * w20, p1 = h * w21, p2 = h * w22, p3 = h * w23;
      p0 += SWZ(p0, 1); p1 += SWZ(p1, 1); p2 += SWZ(p2, 1); p3 += SWZ(p3, 1);
      p0 += SWZ(p0, 2); p1 += SWZ(p1, 2); p2 += SWZ(p2, 2); p3 += SWZ(p3, 2);
      p0 += SWZ(p0, 4); p1 += SWZ(p1, 4); p2 += SWZ(p2, 4); p3 += SWZ(p3, 4);
      p0 += SWZ(p0, 8); p1 += SWZ(p1, 8); p2 += SWZ(p2, 8); p3 += SWZ(p3, 8);
      const float pc01 = b01 ? p1 : p0;
      const float pc23 = b01 ? p3 : p2;
      const float pl = fabsf((b23 ? pc23 : pc01) + bp2c);

      // temp_diffs: gather 5 conducts of row ur, temps = {s*, x5, x6}
      const float ga  = bperm(g, gi0);
      const float gb2 = bperm(g, gi1);
      const float gc2 = bperm(g, gi2);
      const float gd  = bperm(g, gi3);
      const float ge  = bperm(g, gi4);
      const float ta = m0 ? s1 : s0;
      const float tb = m1 ? s2 : s1;
      const float tc = m2 ? s3 : s2;
      const float td = fmaf(ta - sown, ga,
                       fmaf(tb - sown, gb2,
                       fmaf(tc - sown, gc2,
                       fmaf(x5 - sown, gd, (x6 - sown) * ge))));

      // emit prev state (outs[t] = state before consuming x_t)
      if (isrow) op[t * 4] = sown;

      // Euler update + clip
      float nw = fmaf(kcap, td + pl, sown);
      nw = fminf(fmaxf(nw, -1.0f), 5.0f);

      // broadcast new state to all lanes of the group
      s0 = bperm(nw, bi0);
      s1 = bperm(nw, bi1);
      s2 = bperm(nw, bi2);
      s3 = bperm(nw, bi3);
      sown = nw;   // lanes 4..15 carry exact replicas of row (u&3)
    }

    if (c < 7) WRITEC((c + 1) & 1);   // commit prefetched chunk to other buffer
  }
}

extern "C" void kernel_launch(void* const* d_in, const int* in_sizes, int n_in,
                              void* d_out, int out_size, void* d_ws, size_t ws_size,
                              hipStream_t stream) {
  const float* in   = (const float*)d_in[0];
  const float* caps = (const float*)d_in[1];
  const float* Wg   = (const float*)d_in[2];
  const float* bg   = (const float*)d_in[3];
  const float* Wp1  = (const float*)d_in[4];
  const float* bp1  = (const float*)d_in[5];
  const float* Wp2  = (const float*)d_in[6];
  const float* bp2  = (const float*)d_in[7];
  float* out = (float*)d_out;

  hipLaunchKernelGGL(tnn_scan, dim3(1024), dim3(64), 0, stream,
                     in, caps, Wg, bg, Wp1, bp1, Wp2, bp2, out);
}

// Round 2
// 271.502 us; speedup vs baseline: 1.0775x; 1.0775x over previous
//
#include <hip/hip_runtime.h>

// TNNCell scan: B=4096 chains, T=512 steps, 16 lanes/chain, 4 chains/wave.
// grid = 1024 blocks x 64 threads (1 wave/block) -> 1024 waves = 1 wave/SIMD.
//
// R2: recurrence is 100% VALU. Cross-lane reductions use DPP (quad_perm +
// row_ror) instead of ds_swizzle/ds_bpermute (R1 was DS-latency-bound:
// ~6 dependent DS stages x ~120cyc = ~700cyc/step of serial LDS latency).
// Conduct "gather" inverted into per-lane scatter + DPP all-reduce; every
// lane ends each step holding all 4 row states locally (no broadcast).

template <int CTRL>
__device__ __forceinline__ float dppadd(float v) {
  int x = __builtin_amdgcn_update_dpp(0, __float_as_int(v), CTRL, 0xF, 0xF, true);
  return v + __int_as_float(x);
}
#define DPP_XOR1 0xB1   // quad_perm [1,0,3,2]
#define DPP_XOR2 0x4E   // quad_perm [2,3,0,1]
#define DPP_ROR4 0x124  // row_ror:4
#define DPP_ROR8 0x128  // row_ror:8

__global__ __launch_bounds__(64, 1) void tnn_scan(
    const float* __restrict__ in,    // (4096, 512, 7)
    const float* __restrict__ caps,  // (1, 4)
    const float* __restrict__ Wg,    // (11, 15)
    const float* __restrict__ bg,    // (15)
    const float* __restrict__ Wp1,   // (11, 16)
    const float* __restrict__ bp1,   // (16)
    const float* __restrict__ Wp2,   // (16, 4)
    const float* __restrict__ bp2,   // (4)
    float* __restrict__ out)         // (4096, 512, 4)
{
  // LDS x-stage: 2 buffers x 4 chains x 448 dwords (+1 pad -> bank spread).
  __shared__ float xb[2][4][449];

  const int lane = threadIdx.x;   // 0..63
  const int grp  = lane >> 4;     // chain within wave
  const int u    = lane & 15;     // unit lane within chain
  const int ur   = u & 3;

  const int elem = (int)blockIdx.x * 4 + grp;

  // ---- per-lane weight columns ----
  const int ug = (u < 15) ? u : 14;  // conduct col (14 = pair(4,5), dead)
  const float wg0 = Wg[0*15+ug], wg1 = Wg[1*15+ug], wg2 = Wg[2*15+ug],
              wg3 = Wg[3*15+ug], wg4 = Wg[4*15+ug], wg5 = Wg[5*15+ug],
              wg6 = Wg[6*15+ug], wg7 = Wg[7*15+ug], wg8 = Wg[8*15+ug],
              wg9 = Wg[9*15+ug], wg10 = Wg[10*15+ug];
  const float bgc = bg[ug];
  const float wp0 = Wp1[0*16+u], wp1 = Wp1[1*16+u], wp2 = Wp1[2*16+u],
              wp3 = Wp1[3*16+u], wp4 = Wp1[4*16+u], wp5 = Wp1[5*16+u],
              wp6 = Wp1[6*16+u], wp7 = Wp1[7*16+u], wp8 = Wp1[8*16+u],
              wp9 = Wp1[9*16+u], wp10 = Wp1[10*16+u];
  const float bhc = bp1[u];
  const float w20 = Wp2[u*4+0], w21 = Wp2[u*4+1], w22 = Wp2[u*4+2], w23 = Wp2[u*4+3];

  // every lane updates all 4 rows
  const float b20 = bp2[0], b21 = bp2[1], b22 = bp2[2], b23 = bp2[3];
  const float LN10 = 2.302585092994046f;
  const float kc0 = 0.5f * __expf(caps[0] * LN10);
  const float kc1 = 0.5f * __expf(caps[1] * LN10);
  const float kc2 = 0.5f * __expf(caps[2] * LN10);
  const float kc3 = 0.5f * __expf(caps[3] * LN10);

  // ---- conduct pair (pi,pj) for this lane's conduct index u ----
  // idx: 0:(0,1) 1:(0,2) 2:(0,3) 3:(0,4) 4:(0,5) 5:(1,2) 6:(1,3) 7:(1,4)
  //      8:(1,5) 9:(2,3) 10:(2,4) 11:(2,5) 12:(3,4) 13:(3,5) 14:(4,5)
  const unsigned long long IPACK = 0x4433222111100000ULL;
  const unsigned long long JPACK = 0x5554543543254321ULL;
  const int pi = (int)((IPACK >> (4 * u)) & 15);
  const int pj = (int)((JPACK >> (4 * u)) & 15);
  // row-i selectors (pi==4 for dead lanes -> all zero)
  const float is0 = (pi == 0) ? 1.f : 0.f, is1 = (pi == 1) ? 1.f : 0.f,
              is2 = (pi == 2) ? 1.f : 0.f, is3 = (pi == 3) ? 1.f : 0.f;
  // T_j / row-j selectors (pj in 1..5)
  const float tj1 = (pj == 1) ? 1.f : 0.f, tj2 = (pj == 2) ? 1.f : 0.f,
              tj3 = (pj == 3) ? 1.f : 0.f, tj4 = (pj == 4) ? 1.f : 0.f,
              tj5 = (pj == 5) ? 1.f : 0.f;

  // ---- state: all 4 rows replicated on every lane ----
  float s0 = 0.f, s1 = 0.f, s2 = 0.f, s3 = 0.f;

  const float* inblk = in + (size_t)((int)blockIdx.x * 4) * 3584;  // 512*7
  float* op = out + (size_t)elem * 2048 + ur;                      // 512*4

  // ---- chunked double-buffered staging (per-wave, no barriers) ----
  float stg[4][7];
  auto LOADC = [&](int cc) {
    #pragma unroll
    for (int e = 0; e < 4; ++e)
      #pragma unroll
      for (int k = 0; k < 7; ++k)
        stg[e][k] = inblk[(size_t)e * 3584 + cc * 448 + k * 64 + lane];
  };
  auto WRITEC = [&](int bb) {
    #pragma unroll
    for (int e = 0; e < 4; ++e)
      #pragma unroll
      for (int k = 0; k < 7; ++k)
        xb[bb][e][k * 64 + lane] = stg[e][k];
  };

  LOADC(0);
  WRITEC(0);

  #pragma unroll 1
  for (int c = 0; c < 8; ++c) {
    if (c < 7) LOADC(c + 1);          // prefetch next chunk (64 steps of slack)
    const int cb = c & 1;

    #pragma unroll 4
    for (int tin = 0; tin < 64; ++tin) {
      const int t = c * 64 + tin;
      const float* xr = &xb[cb][grp][tin * 7];
      const float x0 = xr[0], x1 = xr[1], x2 = xr[2], x3 = xr[3],
                  x4 = xr[4], x5 = xr[5], x6 = xr[6];

      // x-only parts (off the dependency chain)
      float zgx = fmaf(x0, wg0, fmaf(x1, wg1, fmaf(x2, wg2, fmaf(x3, wg3,
                  fmaf(x4, wg4, fmaf(x5, wg9, fmaf(x6, wg10, bgc)))))));
      float zhx = fmaf(x0, wp0, fmaf(x1, wp1, fmaf(x2, wp2, fmaf(x3, wp3,
                  fmaf(x4, wp4, fmaf(x5, wp9, fmaf(x6, wp10, bhc)))))));
      float txx = fmaf(tj4, x5, tj5 * x6);

      // s-dependent dots
      const float zg = fmaf(s0, wg5, fmaf(s1, wg6, fmaf(s2, wg7, fmaf(s3, wg8, zgx))));
      const float zh = fmaf(s0, wp5, fmaf(s1, wp6, fmaf(s2, wp7, fmaf(s3, wp8, zhx))));

      const float g = __fdividef(1.0f, 1.0f + __expf(-zg));                      // sigmoid
      const float h = 1.0f - 2.0f * __fdividef(1.0f, 1.0f + __expf(2.0f * zh)); // tanh

      // ploss contributions (h-unit u, all 4 output cols)
      float p0 = h * w20, p1 = h * w21, p2 = h * w22, p3 = h * w23;

      // temp-diff contributions of this lane's conduct (pair pi,pj):
      //   row pi: (T_pj - s_pi) * g ;  row pj (if <4): (s_pi - s_pj) * g
      const float sjp = fmaf(tj1, s1, fmaf(tj2, s2, tj3 * s3)); // s_pj (or 0)
      const float Si  = fmaf(is0, s0, fmaf(is1, s1, fmaf(is2, s2, is3 * s3)));
      const float Tj  = sjp + txx;
      const float ci  = g * (Tj - Si);
      const float cj  = g * (Si - sjp);
      float t0 = is0 * ci;
      float t1 = fmaf(is1, ci, tj1 * cj);
      float t2 = fmaf(is2, ci, tj2 * cj);
      float t3 = fmaf(is3, ci, tj3 * cj);

      // 16-lane all-reduce of 8 values, pure DPP (no LDS)
      p0 = dppadd<DPP_XOR1>(p0); p1 = dppadd<DPP_XOR1>(p1);
      p2 = dppadd<DPP_XOR1>(p2); p3 = dppadd<DPP_XOR1>(p3);
      t0 = dppadd<DPP_XOR1>(t0); t1 = dppadd<DPP_XOR1>(t1);
      t2 = dppadd<DPP_XOR1>(t2); t3 = dppadd<DPP_XOR1>(t3);
      p0 = dppadd<DPP_XOR2>(p0); p1 = dppadd<DPP_XOR2>(p1);
      p2 = dppadd<DPP_XOR2>(p2); p3 = dppadd<DPP_XOR2>(p3);
      t0 = dppadd<DPP_XOR2>(t0); t1 = dppadd<DPP_XOR2>(t1);
      t2 = dppadd<DPP_XOR2>(t2); t3 = dppadd<DPP_XOR2>(t3);
      p0 = dppadd<DPP_ROR4>(p0); p1 = dppadd<DPP_ROR4>(p1);
      p2 = dppadd<DPP_ROR4>(p2); p3 = dppadd<DPP_ROR4>(p3);
      t0 = dppadd<DPP_ROR4>(t0); t1 = dppadd<DPP_ROR4>(t1);
      t2 = dppadd<DPP_ROR4>(t2); t3 = dppadd<DPP_ROR4>(t3);
      p0 = dppadd<DPP_ROR8>(p0); p1 = dppadd<DPP_ROR8>(p1);
      p2 = dppadd<DPP_ROR8>(p2); p3 = dppadd<DPP_ROR8>(p3);
      t0 = dppadd<DPP_ROR8>(t0); t1 = dppadd<DPP_ROR8>(t1);
      t2 = dppadd<DPP_ROR8>(t2); t3 = dppadd<DPP_ROR8>(t3);

      // emit prev state (outs[t] = state before consuming x_t)
      const float sout = (ur == 0) ? s0 : (ur == 1) ? s1 : (ur == 2) ? s2 : s3;
      if (u < 4) op[t * 4] = sout;

      // Euler update + clip, all rows locally on every lane
      const float pl0 = fabsf(p0 + b20);
      const float pl1 = fabsf(p1 + b21);
      const float pl2 = fabsf(p2 + b22);
      const float pl3 = fabsf(p3 + b23);
      s0 = fminf(fmaxf(fmaf(kc0, t0 + pl0, s0), -1.0f), 5.0f);
      s1 = fminf(fmaxf(fmaf(kc1, t1 + pl1, s1), -1.0f), 5.0f);
      s2 = fminf(fmaxf(fmaf(kc2, t2 + pl2, s2), -1.0f), 5.0f);
      s3 = fminf(fmaxf(fmaf(kc3, t3 + pl3, s3), -1.0f), 5.0f);
    }

    if (c < 7) WRITEC((c + 1) & 1);   // commit prefetched chunk to other buffer
  }
}

extern "C" void kernel_launch(void* const* d_in, const int* in_sizes, int n_in,
                              void* d_out, int out_size, void* d_ws, size_t ws_size,
                              hipStream_t stream) {
  const float* in   = (const float*)d_in[0];
  const float* caps = (const float*)d_in[1];
  const float* Wg   = (const float*)d_in[2];
  const float* bg   = (const float*)d_in[3];
  const float* Wp1  = (const float*)d_in[4];
  const float* bp1  = (const float*)d_in[5];
  const float* Wp2  = (const float*)d_in[6];
  const float* bp2  = (const float*)d_in[7];
  float* out = (float*)d_out;

  hipLaunchKernelGGL(tnn_scan, dim3(1024), dim3(64), 0, stream,
                     in, caps, Wg, bg, Wp1, bp1, Wp2, bp2, out);
}